// Round 2
// baseline (541.978 us; speedup 1.0000x reference)
//
#include <hip/hip_runtime.h>
#include <stdint.h>

// Problem constants (B,T,C,H,D) = (4,2048,1024,16,64)
#define Bb 4
#define Tt 2048
#define Cc 1024
#define Hh 16
#define Dd 64

using bf16x8 = __bf16 __attribute__((ext_vector_type(8)));
using f32x4  = float  __attribute__((ext_vector_type(4)));
typedef short s16x4 __attribute__((ext_vector_type(4)));
typedef unsigned short u16;

// 16x16x16 bf16 MFMA (K=16): builtin if present, else raw asm (ISA-doc mnemonic).
#if defined(__has_builtin) && __has_builtin(__builtin_amdgcn_mfma_f32_16x16x16bf16_1k)
#define MFMA_16x16x16_BF16(a, b, c) __builtin_amdgcn_mfma_f32_16x16x16bf16_1k(a, b, c, 0, 0, 0)
#else
static __device__ __forceinline__ f32x4 mfma16x16x16bf16_asm(s16x4 a, s16x4 b, f32x4 c) {
  f32x4 d;
  asm volatile("v_mfma_f32_16x16x16_bf16 %0, %1, %2, %3" : "=v"(d) : "v"(a), "v"(b), "v"(c));
  return d;
}
#define MFMA_16x16x16_BF16(a, b, c) mfma16x16x16bf16_asm(a, b, c)
#endif

__device__ __forceinline__ u16 f32_to_bf16(float f) {
  union { float f; unsigned u; } v; v.f = f;
  unsigned r = v.u + 0x7fffu + ((v.u >> 16) & 1u);  // RNE
  return (u16)(r >> 16);
}
__device__ __forceinline__ short bf16rn(float f) {   // round-nearest (no tie handling)
  union { float f; unsigned u; } v; v.f = f;
  return (short)((v.u + 0x8000u) >> 16);
}

// ---------------- cast fp32 -> bf16 (4 elem / thread) ----------------
__global__ void cast_f32_to_bf16(const float* __restrict__ in, u16* __restrict__ out, int n) {
  int i = (blockIdx.x * blockDim.x + threadIdx.x) * 4;
  if (i >= n) return;
  float4 v = *reinterpret_cast<const float4*>(in + i);
  ushort4 o;
  o.x = f32_to_bf16(v.x); o.y = f32_to_bf16(v.y);
  o.z = f32_to_bf16(v.z); o.w = f32_to_bf16(v.w);
  *reinterpret_cast<ushort4*>(out + i) = o;
}

// ---------------- GEMM: C[M,N] = (A[M,K] * B[N,K]^T + bias) * scale ----------------
template<bool OUT_BF16>
__global__ __launch_bounds__(256, 2)
void gemm_bt(const u16* __restrict__ A, const u16* __restrict__ Bw,
             const float* __restrict__ bias, void* __restrict__ Cout,
             int M, int N, int K, float scale)
{
  constexpr int BK  = 32;
  constexpr int LDA = BK + 8;
  __shared__ u16 As[128 * LDA];
  __shared__ u16 Bs[128 * LDA];
  const int tid  = threadIdx.x;
  const int wave = tid >> 6, lane = tid & 63;
  const int row0 = blockIdx.x * 128, col0 = blockIdx.y * 128;
  const int wm = (wave & 1) * 64, wn = (wave >> 1) * 64;
  const int fr = lane & 15, fk = (lane >> 4) * 8;
  const int srow = tid >> 2, scol = (tid & 3) * 8;

  f32x4 acc[4][4] = {};

  for (int k0 = 0; k0 < K; k0 += BK) {
#pragma unroll
    for (int c = 0; c < 2; ++c) {
      int r = c * 64 + srow;
      *reinterpret_cast<uint4*>(&As[r * LDA + scol]) =
          *reinterpret_cast<const uint4*>(A + (size_t)(row0 + r) * K + k0 + scol);
      *reinterpret_cast<uint4*>(&Bs[r * LDA + scol]) =
          *reinterpret_cast<const uint4*>(Bw + (size_t)(col0 + r) * K + k0 + scol);
    }
    __syncthreads();
    bf16x8 af[4], bf[4];
#pragma unroll
    for (int i = 0; i < 4; ++i) {
      af[i] = *reinterpret_cast<const bf16x8*>(&As[(wm + i * 16 + fr) * LDA + fk]);
      bf[i] = *reinterpret_cast<const bf16x8*>(&Bs[(wn + i * 16 + fr) * LDA + fk]);
    }
#pragma unroll
    for (int i = 0; i < 4; ++i)
#pragma unroll
      for (int j = 0; j < 4; ++j)
        acc[i][j] = __builtin_amdgcn_mfma_f32_16x16x32_bf16(af[i], bf[j], acc[i][j], 0, 0, 0);
    __syncthreads();
  }

#pragma unroll
  for (int j = 0; j < 4; ++j) {
    int col = col0 + wn + j * 16 + fr;
    float bv = bias[col];
#pragma unroll
    for (int i = 0; i < 4; ++i) {
      int rowb = row0 + wm + i * 16 + (lane >> 4) * 4;
#pragma unroll
      for (int r = 0; r < 4; ++r) {
        float v = (acc[i][j][r] + bv) * scale;
        size_t idx = (size_t)(rowb + r) * N + col;
        if (OUT_BF16) reinterpret_cast<u16*>(Cout)[idx] = f32_to_bf16(v);
        else          reinterpret_cast<float*>(Cout)[idx] = v;
      }
    }
  }
}

// ---------------- transpose v [B,T,C] -> VT [B,H,D,T] ----------------
__global__ __launch_bounds__(256)
void transpose_v(const u16* __restrict__ V, u16* __restrict__ VT) {
  __shared__ u16 Ts[64 * 72];
  const int tid = threadIdx.x;
  const int tt = blockIdx.x, bh = blockIdx.y;
  const int b = bh >> 4, h = bh & 15;
  const size_t vbase = (size_t)b * Tt * Cc + (size_t)h * Dd + (size_t)tt * 64 * Cc;
#pragma unroll
  for (int it = 0; it < 2; ++it) {
    int c = it * 256 + tid;
    int r = c >> 3, cc = (c & 7) * 8;
    *reinterpret_cast<uint4*>(&Ts[r * 72 + cc]) =
        *reinterpret_cast<const uint4*>(V + vbase + (size_t)r * Cc + cc);
  }
  __syncthreads();
  const size_t obase = (size_t)bh * Dd * Tt + (size_t)tt * 64;
#pragma unroll
  for (int it = 0; it < 2; ++it) {
    int c = it * 256 + tid;
    int dd = c >> 3, cc = (c & 7) * 8;
    alignas(16) u16 tmp[8];
#pragma unroll
    for (int j = 0; j < 8; ++j) tmp[j] = Ts[(cc + j) * 72 + dd];
    *reinterpret_cast<uint4*>(VT + obase + (size_t)dd * Tt + cc) =
        *reinterpret_cast<const uint4*>(tmp);
  }
}

// ---------------- flash attention, transposed-S formulation ----------------
// grid (T/64, B*H), 256 threads. Wave w owns q-cols [qt*64+w*16, +16).
// S^T = K*Q^T via operand swap -> lane holds one q-column, keys in regs.
// Softmax: in-register tree + shfl_xor(16,32) only. P^T feeds PV directly
// (C-layout of 16x16x32 == B-layout of 16x16x16). O^T accumulated, LDS
// transpose once per block in the epilogue.
// Q must arrive pre-scaled by (1/sqrt(D))*log2(e) (folded into projection).
__global__ __launch_bounds__(256, 4)
void attn_kernel(const u16* __restrict__ Q, const u16* __restrict__ Kmat,
                 const u16* __restrict__ VT, u16* __restrict__ O) {
  constexpr int LDK = 72, LDV = 72;
  __shared__ u16 Ks[64 * LDK];   // [key][d]; reused as O-transpose scratch
  __shared__ u16 Vs[64 * LDV];   // [d][key]
  const int tid = threadIdx.x, wave = tid >> 6, lane = tid & 63;
  const int qt = blockIdx.x, bh = blockIdx.y;
  const int b = bh >> 4, h = bh & 15;
  const size_t base = (size_t)b * Tt * Cc + (size_t)h * Dd;
  const int q0 = qt * 64 + wave * 16;
  const int fr = lane & 15, qd = lane >> 4, fk = qd * 8;

  // Q fragment (B-operand of S^T mfma): B[k=d][n=q] == Q[q0+fr][fk..]
  bf16x8 bq0 = *reinterpret_cast<const bf16x8*>(Q + base + (size_t)(q0 + fr) * Cc + fk);
  bf16x8 bq1 = *reinterpret_cast<const bf16x8*>(Q + base + (size_t)(q0 + fr) * Cc + 32 + fk);

  f32x4 Oacc[4] = {};                 // O^T[d = dblock*16 + qd*4 + r][q = q0+fr]
  float mrun = -1e30f, lrun = 0.f;
  const size_t vtb = (size_t)bh * Dd * Tt;

  // staging: thread covers rows r = {tid>>3, 32+tid>>3}, cols (tid&7)*8
  const int sr = tid >> 3, sc = (tid & 7) * 8;
  uint4 kreg[2], vreg[2];
  {
#pragma unroll
    for (int it = 0; it < 2; ++it) {
      int r = it * 32 + sr;
      kreg[it] = *reinterpret_cast<const uint4*>(Kmat + base + (size_t)r * Cc + sc);
      vreg[it] = *reinterpret_cast<const uint4*>(VT + vtb + (size_t)r * Tt + sc);
    }
  }

  for (int kt = 0; kt < Tt; kt += 64) {
#pragma unroll
    for (int it = 0; it < 2; ++it) {
      int r = it * 32 + sr;
      *reinterpret_cast<uint4*>(&Ks[r * LDK + sc]) = kreg[it];
      *reinterpret_cast<uint4*>(&Vs[r * LDV + sc]) = vreg[it];
    }
    __syncthreads();

    if (kt + 64 < Tt) {   // prefetch next tile into regs (overlaps compute)
#pragma unroll
      for (int it = 0; it < 2; ++it) {
        int r = it * 32 + sr;
        kreg[it] = *reinterpret_cast<const uint4*>(Kmat + base + (size_t)(kt + 64 + r) * Cc + sc);
        vreg[it] = *reinterpret_cast<const uint4*>(VT + vtb + (size_t)r * Tt + kt + 64 + sc);
      }
    }

    // S^T[key][q]: A = K frag (m=key), B = Q frag (n=q)
    f32x4 st[4];
#pragma unroll
    for (int kb = 0; kb < 4; ++kb) {
      bf16x8 ak0 = *reinterpret_cast<const bf16x8*>(&Ks[(kb * 16 + fr) * LDK + fk]);
      bf16x8 ak1 = *reinterpret_cast<const bf16x8*>(&Ks[(kb * 16 + fr) * LDK + 32 + fk]);
      f32x4 z = {};
      z      = __builtin_amdgcn_mfma_f32_16x16x32_bf16(ak0, bq0, z, 0, 0, 0);
      st[kb] = __builtin_amdgcn_mfma_f32_16x16x32_bf16(ak1, bq1, z, 0, 0, 0);
    }

    // online softmax, per-lane (one q-column each): in-reg tree + 2 shuffles
    float mx = st[0][0];
#pragma unroll
    for (int kb = 0; kb < 4; ++kb)
#pragma unroll
      for (int r = 0; r < 4; ++r) mx = fmaxf(mx, st[kb][r]);
    mx = fmaxf(mx, __shfl_xor(mx, 16, 64));
    mx = fmaxf(mx, __shfl_xor(mx, 32, 64));
    float mn = fmaxf(mrun, mx);
    float sum = 0.f;
#pragma unroll
    for (int kb = 0; kb < 4; ++kb)
#pragma unroll
      for (int r = 0; r < 4; ++r) {
        float p = exp2f(st[kb][r] - mn);   // Q pre-scaled into log2 domain
        st[kb][r] = p; sum += p;
      }
    sum += __shfl_xor(sum, 16, 64);
    sum += __shfl_xor(sum, 32, 64);
    float alpha = exp2f(mrun - mn);
    lrun = lrun * alpha + sum;
    mrun = mn;
#pragma unroll
    for (int n = 0; n < 4; ++n) Oacc[n] *= alpha;   // alpha per-lane uniform

    // P^T in C-layout == B-operand (K=16) layout: pack regs directly
    s16x4 pf[4];
#pragma unroll
    for (int kb = 0; kb < 4; ++kb)
#pragma unroll
      for (int r = 0; r < 4; ++r) pf[kb][r] = bf16rn(st[kb][r]);

    // O^T += V^T * P^T  (A = V^T frag: m=d, k=key)
#pragma unroll
    for (int kb = 0; kb < 4; ++kb)
#pragma unroll
      for (int n = 0; n < 4; ++n) {
        s16x4 av = *reinterpret_cast<const s16x4*>(&Vs[(n * 16 + fr) * LDV + kb * 16 + qd * 4]);
        Oacc[n] = MFMA_16x16x16_BF16(av, pf[kb], Oacc[n]);
      }
    __syncthreads();
  }

  // epilogue: O^T -> O via LDS (reuse Ks), then coalesced bf16 store
  float linv = 1.0f / lrun;
#pragma unroll
  for (int n = 0; n < 4; ++n)
#pragma unroll
    for (int r = 0; r < 4; ++r)
      Ks[(wave * 16 + fr) * LDK + n * 16 + qd * 4 + r] = f32_to_bf16(Oacc[n][r] * linv);
  __syncthreads();
  {
    int row = tid >> 2, cg = (tid & 3) * 16;
    uint4 a0 = *reinterpret_cast<const uint4*>(&Ks[row * LDK + cg]);
    uint4 a1 = *reinterpret_cast<const uint4*>(&Ks[row * LDK + cg + 8]);
    u16* op = O + base + (size_t)(qt * 64 + row) * Cc + cg;
    *reinterpret_cast<uint4*>(op)     = a0;
    *reinterpret_cast<uint4*>(op + 8) = a1;
  }
}

extern "C" void kernel_launch(void* const* d_in, const int* in_sizes, int n_in,
                              void* d_out, int out_size, void* d_ws, size_t ws_size,
                              hipStream_t stream) {
  const float* x  = (const float*)d_in[0];
  const float* Wq = (const float*)d_in[1];
  const float* bq = (const float*)d_in[2];
  const float* Wk = (const float*)d_in[3];
  const float* bk = (const float*)d_in[4];
  const float* Wv = (const float*)d_in[5];
  const float* bv = (const float*)d_in[6];
  const float* Wo = (const float*)d_in[7];
  const float* bo = (const float*)d_in[8];

  const size_t NX = (size_t)Bb * Tt * Cc;  // 8388608
  const size_t NW = (size_t)Cc * Cc;       // 1048576

  u16* ws  = (u16*)d_ws;
  u16* xb  = ws;
  u16* wqb = ws + NX;
  u16* wkb = wqb + NW;
  u16* wvb = wkb + NW;
  u16* wob = wvb + NW;
  u16* qb  = wob + NW;
  u16* kb  = qb + NX;
  u16* vb  = kb + NX;
  u16* vtb   = xb;  // alias (x dead after projections)
  u16* attnb = vb;  // alias (v dead after transpose)

  cast_f32_to_bf16<<<(int)(NX / 4 / 256), 256, 0, stream>>>(x,  xb,  (int)NX);
  cast_f32_to_bf16<<<(int)(NW / 4 / 256), 256, 0, stream>>>(Wq, wqb, (int)NW);
  cast_f32_to_bf16<<<(int)(NW / 4 / 256), 256, 0, stream>>>(Wk, wkb, (int)NW);
  cast_f32_to_bf16<<<(int)(NW / 4 / 256), 256, 0, stream>>>(Wv, wvb, (int)NW);
  cast_f32_to_bf16<<<(int)(NW / 4 / 256), 256, 0, stream>>>(Wo, wob, (int)NW);

  dim3 gg(64, 8);
  const float QSCL = 0.125f * 1.44269504f;  // 1/sqrt(D) * log2(e), folded into Q
  gemm_bt<true><<<gg, 256, 0, stream>>>(xb, wqb, bq, qb, Bb * Tt, Cc, Cc, QSCL);
  gemm_bt<true><<<gg, 256, 0, stream>>>(xb, wkb, bk, kb, Bb * Tt, Cc, Cc, 1.0f);
  gemm_bt<true><<<gg, 256, 0, stream>>>(xb, wvb, bv, vb, Bb * Tt, Cc, Cc, 1.0f);

  transpose_v<<<dim3(Tt / 64, Bb * Hh), 256, 0, stream>>>(vb, vtb);

  attn_kernel<<<dim3(Tt / 64, Bb * Hh), 256, 0, stream>>>(qb, kb, vtb, attnb);

  gemm_bt<false><<<gg, 256, 0, stream>>>(attnb, wob, bo, d_out, Bb * Tt, Cc, Cc, 1.0f);
}

// Round 3
// 521.354 us; speedup vs baseline: 1.0396x; 1.0396x over previous
//
#include <hip/hip_runtime.h>
#include <stdint.h>

// Problem constants (B,T,C,H,D) = (4,2048,1024,16,64)
#define Bb 4
#define Tt 2048
#define Cc 1024
#define Hh 16
#define Dd 64

using bf16x8 = __bf16 __attribute__((ext_vector_type(8)));
using f32x4  = float  __attribute__((ext_vector_type(4)));
typedef unsigned short u16;
typedef unsigned int   u32;

__device__ __forceinline__ u16 f32_to_bf16(float f) {
  union { float f; unsigned u; } v; v.f = f;
  unsigned r = v.u + 0x7fffu + ((v.u >> 16) & 1u);  // RNE
  return (u16)(r >> 16);
}

// async global->LDS, 16B per lane. LDS dest = wave-uniform base + lane*16.
__device__ __forceinline__ void gl2lds16(const u16* g, u16* l) {
  __builtin_amdgcn_global_load_lds(
      (const __attribute__((address_space(1))) u32*)g,
      (__attribute__((address_space(3))) u32*)l, 16, 0, 0);
}

// ---------------- casts fp32 -> bf16 ----------------
__global__ void cast_f32_to_bf16(const float* __restrict__ in, u16* __restrict__ out, int n) {
  int i = (blockIdx.x * blockDim.x + threadIdx.x) * 4;
  if (i >= n) return;
  float4 v = *reinterpret_cast<const float4*>(in + i);
  ushort4 o;
  o.x = f32_to_bf16(v.x); o.y = f32_to_bf16(v.y);
  o.z = f32_to_bf16(v.z); o.w = f32_to_bf16(v.w);
  *reinterpret_cast<ushort4*>(out + i) = o;
}

// 4 weight matrices in one launch (blockIdx.y selects the matrix)
__global__ void cast4_f32_to_bf16(const float* __restrict__ w0, const float* __restrict__ w1,
                                  const float* __restrict__ w2, const float* __restrict__ w3,
                                  u16* __restrict__ o0, u16* __restrict__ o1,
                                  u16* __restrict__ o2, u16* __restrict__ o3, int n) {
  const float* in; u16* out;
  switch (blockIdx.y) {
    case 0: in = w0; out = o0; break;
    case 1: in = w1; out = o1; break;
    case 2: in = w2; out = o2; break;
    default: in = w3; out = o3; break;
  }
  int i = (blockIdx.x * blockDim.x + threadIdx.x) * 4;
  if (i >= n) return;
  float4 v = *reinterpret_cast<const float4*>(in + i);
  ushort4 o;
  o.x = f32_to_bf16(v.x); o.y = f32_to_bf16(v.y);
  o.z = f32_to_bf16(v.z); o.w = f32_to_bf16(v.w);
  *reinterpret_cast<ushort4*>(out + i) = o;
}

// ---------------- GEMM: C[M,N] = (A[M,K] * B[N,K]^T + bias) * scale ----------------
// m97 recipe: unpadded lane-order LDS + global_load_lds width=16.
// 128x128 tile, BK=32, 4 waves (2x2 of 64x64 each).
template<bool OUT_BF16>
__global__ __launch_bounds__(256, 2)
void gemm_bt(const u16* __restrict__ A, const u16* __restrict__ Bw,
             const float* __restrict__ bias, void* __restrict__ Cout,
             int M, int N, int K, float scale)
{
  constexpr int BK = 32;
  __shared__ alignas(16) u16 As[128 * BK];   // [row][k] contiguous, lane-order
  __shared__ alignas(16) u16 Bs[128 * BK];
  const int tid  = threadIdx.x;
  const int wave = tid >> 6, lane = tid & 63;
  const int row0 = blockIdx.x * 128, col0 = blockIdx.y * 128;
  const int wm = (wave & 1) * 64, wn = (wave >> 1) * 64;
  const int fr = lane & 15, fk = (lane >> 4) * 8;
  const int srow = lane >> 2, scol = (lane & 3) * 8;  // lane covers 16B: row srow, cols scol..scol+7

  f32x4 acc[4][4] = {};

  for (int k0 = 0; k0 < K; k0 += BK) {
#pragma unroll
    for (int c = 0; c < 2; ++c) {
      int rg = (wave * 2 + c) * 16;  // 16-row group staged by this wave-call
      gl2lds16(A  + (size_t)(row0 + rg + srow) * K + k0 + scol, &As[rg * BK]);
      gl2lds16(Bw + (size_t)(col0 + rg + srow) * K + k0 + scol, &Bs[rg * BK]);
    }
    __syncthreads();
    bf16x8 af[4], bf[4];
#pragma unroll
    for (int i = 0; i < 4; ++i) {
      af[i] = *reinterpret_cast<const bf16x8*>(&As[(wm + i * 16 + fr) * BK + fk]);
      bf[i] = *reinterpret_cast<const bf16x8*>(&Bs[(wn + i * 16 + fr) * BK + fk]);
    }
#pragma unroll
    for (int i = 0; i < 4; ++i)
#pragma unroll
      for (int j = 0; j < 4; ++j)
        acc[i][j] = __builtin_amdgcn_mfma_f32_16x16x32_bf16(af[i], bf[j], acc[i][j], 0, 0, 0);
    __syncthreads();
  }

  // C/D layout: col=lane&15, row=(lane>>4)*4+reg (m89-verified)
#pragma unroll
  for (int j = 0; j < 4; ++j) {
    int col = col0 + wn + j * 16 + fr;
    float bv = bias[col];
#pragma unroll
    for (int i = 0; i < 4; ++i) {
      int rowb = row0 + wm + i * 16 + (lane >> 4) * 4;
#pragma unroll
      for (int r = 0; r < 4; ++r) {
        float v = (acc[i][j][r] + bv) * scale;
        size_t idx = (size_t)(rowb + r) * N + col;
        if (OUT_BF16) reinterpret_cast<u16*>(Cout)[idx] = f32_to_bf16(v);
        else          reinterpret_cast<float*>(Cout)[idx] = v;
      }
    }
  }
}

// ---------------- transpose v [B,T,C] -> VT [B,H,D,T] ----------------
__global__ __launch_bounds__(256)
void transpose_v(const u16* __restrict__ V, u16* __restrict__ VT) {
  __shared__ alignas(16) u16 Ts[64 * 72];
  const int tid = threadIdx.x;
  const int tt = blockIdx.x, bh = blockIdx.y;
  const int b = bh >> 4, h = bh & 15;
  const size_t vbase = (size_t)b * Tt * Cc + (size_t)h * Dd + (size_t)tt * 64 * Cc;
#pragma unroll
  for (int it = 0; it < 2; ++it) {
    int c = it * 256 + tid;
    int r = c >> 3, cc = (c & 7) * 8;
    *reinterpret_cast<uint4*>(&Ts[r * 72 + cc]) =
        *reinterpret_cast<const uint4*>(V + vbase + (size_t)r * Cc + cc);
  }
  __syncthreads();
  const size_t obase = (size_t)bh * Dd * Tt + (size_t)tt * 64;
#pragma unroll
  for (int it = 0; it < 2; ++it) {
    int c = it * 256 + tid;
    int dd = c >> 3, cc = (c & 7) * 8;
    alignas(16) u16 tmp[8];
#pragma unroll
    for (int j = 0; j < 8; ++j) tmp[j] = Ts[(cc + j) * 72 + dd];
    *reinterpret_cast<uint4*>(VT + obase + (size_t)dd * Tt + cc) =
        *reinterpret_cast<const uint4*>(tmp);
  }
}

// ---------------- flash attention (round-1 structure, verified 284 us) ----------------
// grid (T/64, B*H), 256 threads. Wave w owns q-rows [qt*64+w*16, +16).
// Q arrives pre-scaled by (1/sqrt(D))*log2(e) (folded into projection).
__global__ __launch_bounds__(256, 2)
void attn_kernel(const u16* __restrict__ Q, const u16* __restrict__ Kmat,
                 const u16* __restrict__ VT, u16* __restrict__ O) {
  constexpr int LDK = 72, LDV = 72, LDP = 68;  // LDP=68: conflict-free P writes
  __shared__ alignas(16) u16 Ks[64 * LDK];   // [key][d]
  __shared__ alignas(16) u16 Vs[64 * LDV];   // [d][key]
  __shared__ alignas(16) u16 Ps[4 * 16 * LDP];
  const int tid = threadIdx.x, wave = tid >> 6, lane = tid & 63;
  const int qt = blockIdx.x, bh = blockIdx.y;
  const int b = bh >> 4, h = bh & 15;
  const size_t base = (size_t)b * Tt * Cc + (size_t)h * Dd;
  const int q0 = qt * 64 + wave * 16;
  const int fr = lane & 15, fk = (lane >> 4) * 8;

  bf16x8 aq0 = *reinterpret_cast<const bf16x8*>(Q + base + (size_t)(q0 + fr) * Cc + fk);
  bf16x8 aq1 = *reinterpret_cast<const bf16x8*>(Q + base + (size_t)(q0 + fr) * Cc + 32 + fk);

  f32x4 Oacc[4] = {};
  float mrow[4] = {-1e30f, -1e30f, -1e30f, -1e30f};
  float lrow[4] = {0.f, 0.f, 0.f, 0.f};
  const size_t vtb = (size_t)bh * Dd * Tt;
  u16* Pw = &Ps[wave * 16 * LDP];

  for (int kt = 0; kt < Tt; kt += 64) {
#pragma unroll
    for (int it = 0; it < 2; ++it) {
      int c = it * 256 + tid;
      int r = c >> 3, cc = (c & 7) * 8;
      *reinterpret_cast<uint4*>(&Ks[r * LDK + cc]) =
          *reinterpret_cast<const uint4*>(Kmat + base + (size_t)(kt + r) * Cc + cc);
      *reinterpret_cast<uint4*>(&Vs[r * LDV + cc]) =
          *reinterpret_cast<const uint4*>(VT + vtb + (size_t)r * Tt + kt + cc);
    }
    __syncthreads();

    // S = Q K^T (16 q-rows x 64 keys); Q pre-scaled into log2 domain
    f32x4 s[4];
#pragma unroll
    for (int j = 0; j < 4; ++j) {
      bf16x8 bk0 = *reinterpret_cast<const bf16x8*>(&Ks[(j * 16 + fr) * LDK + fk]);
      bf16x8 bk1 = *reinterpret_cast<const bf16x8*>(&Ks[(j * 16 + fr) * LDK + 32 + fk]);
      f32x4 z = {};
      z    = __builtin_amdgcn_mfma_f32_16x16x32_bf16(aq0, bk0, z, 0, 0, 0);
      s[j] = __builtin_amdgcn_mfma_f32_16x16x32_bf16(aq1, bk1, z, 0, 0, 0);
    }

    // online softmax; row = (lane>>4)*4 + r, key-col = j*16 + (lane&15)
#pragma unroll
    for (int r = 0; r < 4; ++r) {
      float mx = fmaxf(fmaxf(s[0][r], s[1][r]), fmaxf(s[2][r], s[3][r]));
#pragma unroll
      for (int off = 1; off < 16; off <<= 1) mx = fmaxf(mx, __shfl_xor(mx, off, 64));
      float mn = fmaxf(mrow[r], mx);
      float sum = 0.f;
#pragma unroll
      for (int j = 0; j < 4; ++j) {
        float p = exp2f(s[j][r] - mn);
        s[j][r] = p; sum += p;
      }
#pragma unroll
      for (int off = 1; off < 16; off <<= 1) sum += __shfl_xor(sum, off, 64);
      float alpha = exp2f(mrow[r] - mn);   // first iter: exp2(-huge) = 0
      lrow[r] = lrow[r] * alpha + sum;
      mrow[r] = mn;
#pragma unroll
      for (int n = 0; n < 4; ++n) Oacc[n][r] *= alpha;
    }

    // P: C-layout -> LDS -> A-layout
#pragma unroll
    for (int j = 0; j < 4; ++j)
#pragma unroll
      for (int r = 0; r < 4; ++r)
        Pw[((lane >> 4) * 4 + r) * LDP + j * 16 + fr] = f32_to_bf16(s[j][r]);

    __syncthreads();

#pragma unroll
    for (int kk = 0; kk < 2; ++kk) {
      bf16x8 ap = *reinterpret_cast<const bf16x8*>(&Pw[fr * LDP + kk * 32 + fk]);
#pragma unroll
      for (int n = 0; n < 4; ++n) {
        bf16x8 bv = *reinterpret_cast<const bf16x8*>(&Vs[(n * 16 + fr) * LDV + kk * 32 + fk]);
        Oacc[n] = __builtin_amdgcn_mfma_f32_16x16x32_bf16(ap, bv, Oacc[n], 0, 0, 0);
      }
    }
    __syncthreads();
  }

#pragma unroll
  for (int r = 0; r < 4; ++r) {
    float linv = 1.0f / lrow[r];
    int t = q0 + (lane >> 4) * 4 + r;
#pragma unroll
    for (int n = 0; n < 4; ++n)
      O[base + (size_t)t * Cc + n * 16 + fr] = f32_to_bf16(Oacc[n][r] * linv);
  }
}

extern "C" void kernel_launch(void* const* d_in, const int* in_sizes, int n_in,
                              void* d_out, int out_size, void* d_ws, size_t ws_size,
                              hipStream_t stream) {
  const float* x  = (const float*)d_in[0];
  const float* Wq = (const float*)d_in[1];
  const float* bq = (const float*)d_in[2];
  const float* Wk = (const float*)d_in[3];
  const float* bk = (const float*)d_in[4];
  const float* Wv = (const float*)d_in[5];
  const float* bv = (const float*)d_in[6];
  const float* Wo = (const float*)d_in[7];
  const float* bo = (const float*)d_in[8];

  const size_t NX = (size_t)Bb * Tt * Cc;  // 8388608
  const size_t NW = (size_t)Cc * Cc;       // 1048576

  u16* ws  = (u16*)d_ws;
  u16* xb  = ws;
  u16* wqb = ws + NX;
  u16* wkb = wqb + NW;
  u16* wvb = wkb + NW;
  u16* wob = wvb + NW;
  u16* qb  = wob + NW;
  u16* kb  = qb + NX;
  u16* vb  = kb + NX;
  u16* vtb   = xb;  // alias (x dead after projections)
  u16* attnb = vb;  // alias (v dead after transpose)

  cast_f32_to_bf16<<<(int)(NX / 4 / 256), 256, 0, stream>>>(x, xb, (int)NX);
  cast4_f32_to_bf16<<<dim3((unsigned)(NW / 4 / 256), 4), 256, 0, stream>>>(
      Wq, Wk, Wv, Wo, wqb, wkb, wvb, wob, (int)NW);

  dim3 gg(64, 8);
  const float QSCL = 0.125f * 1.44269504f;  // 1/sqrt(D) * log2(e), folded into Q
  gemm_bt<true><<<gg, 256, 0, stream>>>(xb, wqb, bq, qb, Bb * Tt, Cc, Cc, QSCL);
  gemm_bt<true><<<gg, 256, 0, stream>>>(xb, wkb, bk, kb, Bb * Tt, Cc, Cc, 1.0f);
  gemm_bt<true><<<gg, 256, 0, stream>>>(xb, wvb, bv, vb, Bb * Tt, Cc, Cc, 1.0f);

  transpose_v<<<dim3(Tt / 64, Bb * Hh), 256, 0, stream>>>(vb, vtb);

  attn_kernel<<<dim3(Tt / 64, Bb * Hh), 256, 0, stream>>>(qb, kb, vtb, attnb);

  gemm_bt<false><<<gg, 256, 0, stream>>>(attnb, wob, bo, d_out, Bb * Tt, Cc, Cc, 1.0f);
}

// Round 4
// 371.470 us; speedup vs baseline: 1.4590x; 1.4035x over previous
//
#include <hip/hip_runtime.h>
#include <stdint.h>

// Problem constants (B,T,C,H,D) = (4,2048,1024,16,64)
#define Bb 4
#define Tt 2048
#define Cc 1024
#define Hh 16
#define Dd 64

using bf16x8 = __bf16 __attribute__((ext_vector_type(8)));
using f32x4  = float  __attribute__((ext_vector_type(4)));
typedef short s16x4 __attribute__((ext_vector_type(4)));
typedef unsigned short u16;
typedef unsigned int   u32;

// 16x16x16 bf16 MFMA (K=16)
#if defined(__has_builtin) && __has_builtin(__builtin_amdgcn_mfma_f32_16x16x16bf16_1k)
#define MFMA_16x16x16_BF16(a, b, c) __builtin_amdgcn_mfma_f32_16x16x16bf16_1k(a, b, c, 0, 0, 0)
#else
static __device__ __forceinline__ f32x4 mfma16x16x16bf16_asm(s16x4 a, s16x4 b, f32x4 c) {
  f32x4 d;
  asm volatile("v_mfma_f32_16x16x16_bf16 %0, %1, %2, %3" : "=v"(d) : "v"(a), "v"(b), "v"(c));
  return d;
}
#define MFMA_16x16x16_BF16(a, b, c) mfma16x16x16bf16_asm(a, b, c)
#endif

__device__ __forceinline__ u16 f32_to_bf16(float f) {
  union { float f; unsigned u; } v; v.f = f;
  unsigned r = v.u + 0x7fffu + ((v.u >> 16) & 1u);  // RNE
  return (u16)(r >> 16);
}
__device__ __forceinline__ short bf16rn(float f) {
  union { float f; unsigned u; } v; v.f = f;
  return (short)((v.u + 0x8000u) >> 16);
}

// async global->LDS, 16B per lane. LDS dest = wave-uniform base + lane*16.
__device__ __forceinline__ void gl2lds16(const u16* g, u16* l) {
  __builtin_amdgcn_global_load_lds(
      (const __attribute__((address_space(1))) u32*)g,
      (__attribute__((address_space(3))) u32*)l, 16, 0, 0);
}

// ---------------- casts fp32 -> bf16 ----------------
__global__ void cast_f32_to_bf16(const float* __restrict__ in, u16* __restrict__ out, int n) {
  int i = (blockIdx.x * blockDim.x + threadIdx.x) * 4;
  if (i >= n) return;
  float4 v = *reinterpret_cast<const float4*>(in + i);
  ushort4 o;
  o.x = f32_to_bf16(v.x); o.y = f32_to_bf16(v.y);
  o.z = f32_to_bf16(v.z); o.w = f32_to_bf16(v.w);
  *reinterpret_cast<ushort4*>(out + i) = o;
}

__global__ void cast4_f32_to_bf16(const float* __restrict__ w0, const float* __restrict__ w1,
                                  const float* __restrict__ w2, const float* __restrict__ w3,
                                  u16* __restrict__ o0, u16* __restrict__ o1,
                                  u16* __restrict__ o2, u16* __restrict__ o3, int n) {
  const float* in; u16* out;
  switch (blockIdx.y) {
    case 0: in = w0; out = o0; break;
    case 1: in = w1; out = o1; break;
    case 2: in = w2; out = o2; break;
    default: in = w3; out = o3; break;
  }
  int i = (blockIdx.x * blockDim.x + threadIdx.x) * 4;
  if (i >= n) return;
  float4 v = *reinterpret_cast<const float4*>(in + i);
  ushort4 o;
  o.x = f32_to_bf16(v.x); o.y = f32_to_bf16(v.y);
  o.z = f32_to_bf16(v.z); o.w = f32_to_bf16(v.w);
  *reinterpret_cast<ushort4*>(out + i) = o;
}

// ---------------- GEMM: C[M,N] = (A[M,K] * B[N,K]^T + bias) * scale ----------------
// m97 recipe: unpadded lane-order LDS + global_load_lds width=16.
template<bool OUT_BF16>
__global__ __launch_bounds__(256, 2)
void gemm_bt(const u16* __restrict__ A, const u16* __restrict__ Bw,
             const float* __restrict__ bias, void* __restrict__ Cout,
             int M, int N, int K, float scale)
{
  constexpr int BK = 32;
  __shared__ alignas(16) u16 As[128 * BK];
  __shared__ alignas(16) u16 Bs[128 * BK];
  const int tid  = threadIdx.x;
  const int wave = tid >> 6, lane = tid & 63;
  const int row0 = blockIdx.x * 128, col0 = blockIdx.y * 128;
  const int wm = (wave & 1) * 64, wn = (wave >> 1) * 64;
  const int fr = lane & 15, fk = (lane >> 4) * 8;
  const int srow = lane >> 2, scol = (lane & 3) * 8;

  f32x4 acc[4][4] = {};

  for (int k0 = 0; k0 < K; k0 += BK) {
#pragma unroll
    for (int c = 0; c < 2; ++c) {
      int rg = (wave * 2 + c) * 16;
      gl2lds16(A  + (size_t)(row0 + rg + srow) * K + k0 + scol, &As[rg * BK]);
      gl2lds16(Bw + (size_t)(col0 + rg + srow) * K + k0 + scol, &Bs[rg * BK]);
    }
    __syncthreads();
    bf16x8 af[4], bf[4];
#pragma unroll
    for (int i = 0; i < 4; ++i) {
      af[i] = *reinterpret_cast<const bf16x8*>(&As[(wm + i * 16 + fr) * BK + fk]);
      bf[i] = *reinterpret_cast<const bf16x8*>(&Bs[(wn + i * 16 + fr) * BK + fk]);
    }
#pragma unroll
    for (int i = 0; i < 4; ++i)
#pragma unroll
      for (int j = 0; j < 4; ++j)
        acc[i][j] = __builtin_amdgcn_mfma_f32_16x16x32_bf16(af[i], bf[j], acc[i][j], 0, 0, 0);
    __syncthreads();
  }

#pragma unroll
  for (int j = 0; j < 4; ++j) {
    int col = col0 + wn + j * 16 + fr;
    float bv = bias[col];
#pragma unroll
    for (int i = 0; i < 4; ++i) {
      int rowb = row0 + wm + i * 16 + (lane >> 4) * 4;
#pragma unroll
      for (int r = 0; r < 4; ++r) {
        float v = (acc[i][j][r] + bv) * scale;
        size_t idx = (size_t)(rowb + r) * N + col;
        if (OUT_BF16) reinterpret_cast<u16*>(Cout)[idx] = f32_to_bf16(v);
        else          reinterpret_cast<float*>(Cout)[idx] = v;
      }
    }
  }
}

// ---------------- transpose v [B,T,C] -> VT [B,H,D,T] ----------------
__global__ __launch_bounds__(256)
void transpose_v(const u16* __restrict__ V, u16* __restrict__ VT) {
  __shared__ alignas(16) u16 Ts[64 * 72];
  const int tid = threadIdx.x;
  const int tt = blockIdx.x, bh = blockIdx.y;
  const int b = bh >> 4, h = bh & 15;
  const size_t vbase = (size_t)b * Tt * Cc + (size_t)h * Dd + (size_t)tt * 64 * Cc;
#pragma unroll
  for (int it = 0; it < 2; ++it) {
    int c = it * 256 + tid;
    int r = c >> 3, cc = (c & 7) * 8;
    *reinterpret_cast<uint4*>(&Ts[r * 72 + cc]) =
        *reinterpret_cast<const uint4*>(V + vbase + (size_t)r * Cc + cc);
  }
  __syncthreads();
  const size_t obase = (size_t)bh * Dd * Tt + (size_t)tt * 64;
#pragma unroll
  for (int it = 0; it < 2; ++it) {
    int c = it * 256 + tid;
    int dd = c >> 3, cc = (c & 7) * 8;
    alignas(16) u16 tmp[8];
#pragma unroll
    for (int j = 0; j < 8; ++j) tmp[j] = Ts[(cc + j) * 72 + dd];
    *reinterpret_cast<uint4*>(VT + obase + (size_t)dd * Tt + cc) =
        *reinterpret_cast<const uint4*>(tmp);
  }
}

// ---------------- flash attention, transposed-S (spill-free) ----------------
// grid (T/64, B*H), 256 threads, wave w owns q-cols [qt*64+w*16, +16).
// S^T = K*Q^T via operand swap: lane holds one q-column, keys in regs ->
// softmax is in-register + shfl_xor(16,32) only. P^T (C-layout of K=32 MFMA)
// IS the B-operand layout of the K=16 MFMA -> PV directly from registers.
// Q arrives pre-scaled by (1/sqrt(D))*log2(e).
__global__ __launch_bounds__(256, 2)
void attn_kernel(const u16* __restrict__ Q, const u16* __restrict__ Kmat,
                 const u16* __restrict__ VT, u16* __restrict__ O) {
  constexpr int LDK = 72, LDV = 72;
  __shared__ alignas(16) u16 Ks[64 * LDK];   // [key][d]; reused for O transpose
  __shared__ alignas(16) u16 Vs[64 * LDV];   // [d][key]
  const int tid = threadIdx.x, wave = tid >> 6, lane = tid & 63;
  const int qt = blockIdx.x, bh = blockIdx.y;
  const int b = bh >> 4, h = bh & 15;
  const size_t base = (size_t)b * Tt * Cc + (size_t)h * Dd;
  const int q0 = qt * 64 + wave * 16;
  const int fr = lane & 15, qd = lane >> 4, fk = qd * 8;

  // Q fragment (B-operand of S^T): B[k=d][n=q] == Q[q0+fr][fk..]
  bf16x8 bq0 = *reinterpret_cast<const bf16x8*>(Q + base + (size_t)(q0 + fr) * Cc + fk);
  bf16x8 bq1 = *reinterpret_cast<const bf16x8*>(Q + base + (size_t)(q0 + fr) * Cc + 32 + fk);

  f32x4 Oacc[4] = {};                 // O^T[d = n*16 + qd*4 + r][q = q0+fr]
  float mrun = -1e30f, lrun = 0.f;
  const size_t vtb = (size_t)bh * Dd * Tt;

  for (int kt = 0; kt < Tt; kt += 64) {
#pragma unroll
    for (int it = 0; it < 2; ++it) {
      int c = it * 256 + tid;
      int r = c >> 3, cc = (c & 7) * 8;
      *reinterpret_cast<uint4*>(&Ks[r * LDK + cc]) =
          *reinterpret_cast<const uint4*>(Kmat + base + (size_t)(kt + r) * Cc + cc);
      *reinterpret_cast<uint4*>(&Vs[r * LDV + cc]) =
          *reinterpret_cast<const uint4*>(VT + vtb + (size_t)r * Tt + kt + cc);
    }
    __syncthreads();

    // S^T[key][q]: A = K frag (m=key), B = Q frag (n=q)
    f32x4 st[4];
#pragma unroll
    for (int kb = 0; kb < 4; ++kb) {
      bf16x8 ak0 = *reinterpret_cast<const bf16x8*>(&Ks[(kb * 16 + fr) * LDK + fk]);
      bf16x8 ak1 = *reinterpret_cast<const bf16x8*>(&Ks[(kb * 16 + fr) * LDK + 32 + fk]);
      f32x4 z = {};
      z      = __builtin_amdgcn_mfma_f32_16x16x32_bf16(ak0, bq0, z, 0, 0, 0);
      st[kb] = __builtin_amdgcn_mfma_f32_16x16x32_bf16(ak1, bq1, z, 0, 0, 0);
    }

    // online softmax per-lane (one q-column): in-reg tree + 2 shuffles
    float mx = st[0][0];
#pragma unroll
    for (int kb = 0; kb < 4; ++kb)
#pragma unroll
      for (int r = 0; r < 4; ++r) mx = fmaxf(mx, st[kb][r]);
    mx = fmaxf(mx, __shfl_xor(mx, 16, 64));
    mx = fmaxf(mx, __shfl_xor(mx, 32, 64));
    float mn = fmaxf(mrun, mx);
    float sum = 0.f;
#pragma unroll
    for (int kb = 0; kb < 4; ++kb)
#pragma unroll
      for (int r = 0; r < 4; ++r) {
        float p = exp2f(st[kb][r] - mn);   // Q pre-scaled into log2 domain
        st[kb][r] = p; sum += p;
      }
    sum += __shfl_xor(sum, 16, 64);
    sum += __shfl_xor(sum, 32, 64);
    float alpha = exp2f(mrun - mn);        // first iter: 0
    lrun = lrun * alpha + sum;
    mrun = mn;
#pragma unroll
    for (int n = 0; n < 4; ++n) Oacc[n] *= alpha;

    // P^T: C-layout (row=qd*4+r) == B-operand (k=qd*4+j) of K=16 MFMA
    s16x4 pf[4];
#pragma unroll
    for (int kb = 0; kb < 4; ++kb)
#pragma unroll
      for (int r = 0; r < 4; ++r) pf[kb][r] = bf16rn(st[kb][r]);

    // O^T += V^T * P^T  (A = V^T frag: m=d, k=key)
#pragma unroll
    for (int kb = 0; kb < 4; ++kb)
#pragma unroll
      for (int n = 0; n < 4; ++n) {
        s16x4 av = *reinterpret_cast<const s16x4*>(&Vs[(n * 16 + fr) * LDV + kb * 16 + qd * 4]);
        Oacc[n] = MFMA_16x16x16_BF16(av, pf[kb], Oacc[n]);
      }
    __syncthreads();
  }

  // epilogue: O^T -> O via LDS (reuse Ks), then coalesced store
  float linv = 1.0f / lrun;
#pragma unroll
  for (int n = 0; n < 4; ++n)
#pragma unroll
    for (int r = 0; r < 4; ++r)
      Ks[(wave * 16 + fr) * LDK + n * 16 + qd * 4 + r] = f32_to_bf16(Oacc[n][r] * linv);
  __syncthreads();
  {
    int row = tid >> 2, cg = (tid & 3) * 16;
    uint4 a0 = *reinterpret_cast<const uint4*>(&Ks[row * LDK + cg]);
    uint4 a1 = *reinterpret_cast<const uint4*>(&Ks[row * LDK + cg + 8]);
    u16* op = O + base + (size_t)(qt * 64 + row) * Cc + cg;
    *reinterpret_cast<uint4*>(op)     = a0;
    *reinterpret_cast<uint4*>(op + 8) = a1;
  }
}

extern "C" void kernel_launch(void* const* d_in, const int* in_sizes, int n_in,
                              void* d_out, int out_size, void* d_ws, size_t ws_size,
                              hipStream_t stream) {
  const float* x  = (const float*)d_in[0];
  const float* Wq = (const float*)d_in[1];
  const float* bq = (const float*)d_in[2];
  const float* Wk = (const float*)d_in[3];
  const float* bk = (const float*)d_in[4];
  const float* Wv = (const float*)d_in[5];
  const float* bv = (const float*)d_in[6];
  const float* Wo = (const float*)d_in[7];
  const float* bo = (const float*)d_in[8];

  const size_t NX = (size_t)Bb * Tt * Cc;  // 8388608
  const size_t NW = (size_t)Cc * Cc;       // 1048576

  u16* ws  = (u16*)d_ws;
  u16* xb  = ws;
  u16* wqb = ws + NX;
  u16* wkb = wqb + NW;
  u16* wvb = wkb + NW;
  u16* wob = wvb + NW;
  u16* qb  = wob + NW;
  u16* kb  = qb + NX;
  u16* vb  = kb + NX;
  u16* vtb   = xb;  // alias (x dead after projections)
  u16* attnb = vb;  // alias (v dead after transpose)

  cast_f32_to_bf16<<<(int)(NX / 4 / 256), 256, 0, stream>>>(x, xb, (int)NX);
  cast4_f32_to_bf16<<<dim3((unsigned)(NW / 4 / 256), 4), 256, 0, stream>>>(
      Wq, Wk, Wv, Wo, wqb, wkb, wvb, wob, (int)NW);

  dim3 gg(64, 8);
  const float QSCL = 0.125f * 1.44269504f;  // 1/sqrt(D) * log2(e), folded into Q
  gemm_bt<true><<<gg, 256, 0, stream>>>(xb, wqb, bq, qb, Bb * Tt, Cc, Cc, QSCL);
  gemm_bt<true><<<gg, 256, 0, stream>>>(xb, wkb, bk, kb, Bb * Tt, Cc, Cc, 1.0f);
  gemm_bt<true><<<gg, 256, 0, stream>>>(xb, wvb, bv, vb, Bb * Tt, Cc, Cc, 1.0f);

  transpose_v<<<dim3(Tt / 64, Bb * Hh), 256, 0, stream>>>(vb, vtb);

  attn_kernel<<<dim3(Tt / 64, Bb * Hh), 256, 0, stream>>>(qb, kb, vtb, attnb);

  gemm_bt<false><<<gg, 256, 0, stream>>>(attnb, wob, bo, d_out, Bb * Tt, Cc, Cc, 1.0f);
}